// Round 3
// baseline (1145.681 us; speedup 1.0000x reference)
//
#include <hip/hip_runtime.h>
#include <hip/hip_bf16.h>

#define SEQ 2048
#define BATCH 2
#define NH 16
#define DK 64
#define DM 1024

typedef __bf16 bf16;
typedef __bf16 bf16x8 __attribute__((ext_vector_type(8)));
typedef float f32x4 __attribute__((ext_vector_type(4)));

#define MFMA16(a,b,c) __builtin_amdgcn_mfma_f32_16x16x32_bf16(a,b,c,0,0,0)
#define NEG_BIG (-1.0e30f)

__device__ __forceinline__ bf16x8 ld8(const bf16* p){ return *(const bf16x8*)p; }

// load 8 consecutive f32 and convert to a bf16x8 MFMA fragment
__device__ __forceinline__ bf16x8 ld8f(const float* p){
    f32x4 a = *(const f32x4*)p;
    f32x4 b = *(const f32x4*)(p+4);
    bf16x8 r;
    #pragma unroll
    for (int i=0;i<4;i++){ r[i] = (bf16)a[i]; r[i+4] = (bf16)b[i]; }
    return r;
}

// ---------------------------------------------------------------------------
// QKV projection: C = X @ W^T. X [4096 x 1024] f32 row-major, W [1024 x 1024]
// f32 row-major (both K-contiguous: gemm_bt). f32 -> bf16 cvt on the fly.
//   a_frag[j] = A[m0 + (lane&15)][k0 + (lane>>4)*8 + j]
//   b_frag[j] = B[n0 + (lane&15)][k0 + (lane>>4)*8 + j]   (B stored [N,K])
//   C/D:  row = (lane>>4)*4 + r, col = lane&15
// z=0 -> q_s [B,H,S,dk]; z=1 -> k_s [B,H,S,dk]; z=2 -> vt_s [B,H,dk,S]  (bf16)
// ---------------------------------------------------------------------------
__global__ __launch_bounds__(256) void qkv_proj_kernel(
    const float* __restrict__ Qin, const float* __restrict__ Kin, const float* __restrict__ Vin,
    const float* __restrict__ Wq,  const float* __restrict__ Wk,  const float* __restrict__ Wv,
    bf16* __restrict__ q_s, bf16* __restrict__ k_s, bf16* __restrict__ vt_s)
{
    const int z = blockIdx.z;
    const float* X = (z==0) ? Qin : (z==1) ? Kin : Vin;
    const float* W = (z==0) ? Wq  : (z==1) ? Wk  : Wv;
    bf16* out      = (z==0) ? q_s : (z==1) ? k_s : vt_s;

    const int lane = threadIdx.x & 63;
    const int w    = threadIdx.x >> 6;
    const int lr = lane & 15, lq = lane >> 4;
    const int m0 = blockIdx.y*128 + (w>>1)*64;
    const int n0 = blockIdx.x*128 + (w&1)*64;

    f32x4 acc[4][4] = {};
    const float* Ab = X + (size_t)(m0+lr)*DM + lq*8;
    const float* Bb = W + (size_t)(n0+lr)*DM + lq*8;
    for (int k0 = 0; k0 < DM; k0 += 32) {
        bf16x8 af[4], bfr[4];
        #pragma unroll
        for (int mi=0;mi<4;mi++) af[mi]  = ld8f(Ab + (size_t)mi*16*DM + k0);
        #pragma unroll
        for (int ni=0;ni<4;ni++) bfr[ni] = ld8f(Bb + (size_t)ni*16*DM + k0);
        #pragma unroll
        for (int mi=0;mi<4;mi++)
            #pragma unroll
            for (int ni=0;ni<4;ni++)
                acc[mi][ni] = MFMA16(af[mi], bfr[ni], acc[mi][ni]);
    }
    #pragma unroll
    for (int mi=0;mi<4;mi++)
    #pragma unroll
    for (int ni=0;ni<4;ni++)
    #pragma unroll
    for (int r=0;r<4;r++) {
        int row = m0 + mi*16 + lq*4 + r;       // token index (b*S + s)
        int col = n0 + ni*16 + lr;             // output feature (h*64 + d)
        int b = row >> 11, s = row & (SEQ-1);
        int h = col >> 6,  dd = col & 63;
        size_t idx = (z==2)
          ? ((size_t)((b*NH + h)*DK + dd))*SEQ + s      // v transposed
          : ((size_t)( b*NH + h))*SEQ*DK + (size_t)s*DK + dd;
        out[idx] = (bf16)acc[mi][ni][r];
    }
}

// ---------------------------------------------------------------------------
// Attention: one block = 64 queries of one (b,h). 4 waves x 16 queries each.
// Per-wave LDS only -> barrier-free. All arithmetic FINITE (-1e30 masks).
// Pass 1: row stats (m,l). Pass 2: P -> LDS (bf16 for MFMA A-layout, f32 for
// vectorized float4 attn stores), O += P@V via MFMA. attn out is FLOAT32.
// ---------------------------------------------------------------------------
__device__ __forceinline__ void compute_scores(
    const bf16* __restrict__ kp, const bf16x8* qf,
    int kt, int qt, int qw0, int lr, int lq, f32x4* s)
{
    const f32x4 z4 = {0.f,0.f,0.f,0.f};
    s[0]=z4; s[1]=z4; s[2]=z4; s[3]=z4;
    #pragma unroll
    for (int ks=0; ks<2; ks++) {
        #pragma unroll
        for (int nt=0; nt<4; nt++) {
            bf16x8 kf = ld8(kp + (size_t)(kt*64 + nt*16 + lr)*DK + ks*32 + lq*8);
            s[nt] = MFMA16(qf[ks], kf, s[nt]);
        }
    }
    #pragma unroll
    for (int nt=0; nt<4; nt++)
        #pragma unroll
        for (int r=0; r<4; r++) {
            float v = s[nt][r]*0.125f;                       // 1/sqrt(64)
            // C-layout: row (query) = lq*4+r, col (key) = lr
            if (kt==qt && (kt*64 + nt*16 + lr) > (qw0 + lq*4 + r))
                v = NEG_BIG;
            s[nt][r] = v;
        }
}

__global__ __launch_bounds__(256) void attn_kernel(
    const bf16* __restrict__ q_s, const bf16* __restrict__ k_s,
    const bf16* __restrict__ vt_s,
    float* __restrict__ attn_out, bf16* __restrict__ ao)
{
    __shared__ bf16  P [4][16][72];   // per-wave bf16 P tile (MFMA A reads)
    __shared__ float Pf[4][16][68];   // per-wave f32 P tile (vector stores)
    const int qt = blockIdx.x, bh = blockIdx.y;
    const int lane = threadIdx.x & 63, w = threadIdx.x >> 6;
    const int lr = lane & 15, lq = lane >> 4;
    const bf16* qp = q_s  + (size_t)bh*SEQ*DK;
    const bf16* kp = k_s  + (size_t)bh*SEQ*DK;
    const bf16* vp = vt_s + (size_t)bh*DK*SEQ;
    float* ab = attn_out + (size_t)bh*SEQ*SEQ;
    const int q0 = qt*64;
    const int qw0 = q0 + w*16;

    bf16x8 qf[2];
    qf[0] = ld8(qp + (size_t)(qw0+lr)*DK + lq*8);
    qf[1] = ld8(qp + (size_t)(qw0+lr)*DK + 32 + lq*8);

    float m_r[4], l_r[4];
    #pragma unroll
    for (int r=0;r<4;r++){ m_r[r] = NEG_BIG; l_r[r] = 0.f; }

    // ---- pass 1: row stats ----
    for (int kt=0; kt<=qt; kt++) {
        f32x4 s[4];
        compute_scores(kp, qf, kt, qt, qw0, lr, lq, s);
        #pragma unroll
        for (int r=0;r<4;r++){
            float tm = fmaxf(fmaxf(s[0][r],s[1][r]), fmaxf(s[2][r],s[3][r]));
            tm = fmaxf(tm, __shfl_xor(tm,1));
            tm = fmaxf(tm, __shfl_xor(tm,2));
            tm = fmaxf(tm, __shfl_xor(tm,4));
            tm = fmaxf(tm, __shfl_xor(tm,8));
            float mn = fmaxf(m_r[r], tm);
            float sm = __expf(s[0][r]-mn)+__expf(s[1][r]-mn)
                     + __expf(s[2][r]-mn)+__expf(s[3][r]-mn);
            sm += __shfl_xor(sm,1); sm += __shfl_xor(sm,2);
            sm += __shfl_xor(sm,4); sm += __shfl_xor(sm,8);
            l_r[r] = l_r[r]*__expf(m_r[r]-mn) + sm;
            m_r[r] = mn;
        }
    }
    float inv_l[4];
    #pragma unroll
    for (int r=0;r<4;r++) inv_l[r] = 1.0f / fmaxf(l_r[r], 1e-20f);

    // ---- pass 2: attn write (f32) + O accumulate ----
    f32x4 o[4] = {};
    for (int kt=0; kt<=qt; kt++) {
        f32x4 s[4];
        compute_scores(kp, qf, kt, qt, qw0, lr, lq, s);
        #pragma unroll
        for (int nt=0;nt<4;nt++)
            #pragma unroll
            for (int r=0;r<4;r++){
                float p = __expf(s[nt][r]-m_r[r]) * inv_l[r];
                P [w][lq*4+r][nt*16+lr] = (bf16)p;
                Pf[w][lq*4+r][nt*16+lr] = p;
            }
        __asm__ __volatile__("" ::: "memory");   // keep LDS writes before reads
        // vectorized attn store: 4 x float4 per lane from f32 LDS (same wave;
        // DS pipe is in-order per wave)
        #pragma unroll
        for (int t=0;t<4;t++){
            int row  = t*4 + lq;
            int col4 = lr*4;
            *(f32x4*)(ab + (size_t)(qw0+row)*SEQ + kt*64 + col4)
                = *(const f32x4*)(&Pf[w][row][col4]);
        }
        #pragma unroll
        for (int ks=0;ks<2;ks++){
            bf16x8 pf = *(const bf16x8*)(&P[w][lr][ks*32 + lq*8]);  // A-layout
            #pragma unroll
            for (int nt=0;nt<4;nt++){
                bf16x8 vf = ld8(vp + (size_t)(nt*16+lr)*SEQ + kt*64 + ks*32 + lq*8);
                o[nt] = MFMA16(pf, vf, o[nt]);
            }
        }
    }

    const int b = bh >> 4, h = bh & 15;
    #pragma unroll
    for (int nt=0;nt<4;nt++)
        #pragma unroll
        for (int r=0;r<4;r++){
            int qrow = qw0 + lq*4 + r;
            ao[(size_t)(b*SEQ + qrow)*DM + h*64 + nt*16 + lr] = (bf16)o[nt][r];
        }

    // ---- zero-fill strictly-upper attn tiles (f32, 16B chunks) ----
    int zc0 = (qt+1)*64;
    if (zc0 < SEQ) {
        int zw4 = (SEQ - zc0) >> 2;      // float4 chunks per row
        int total = 64 * zw4;
        const f32x4 z4 = {0.f,0.f,0.f,0.f};
        for (int i = threadIdx.x; i < total; i += 256) {
            int row = i / zw4;
            int cc  = (i - row*zw4) << 2;
            *(f32x4*)(ab + (size_t)(q0+row)*SEQ + zc0 + cc) = z4;
        }
    }
}

// ---------------------------------------------------------------------------
// Output projection: out = AO @ Wo^T + bo. AO bf16 [4096 x 1024], Wo f32
// (cvt on the fly), bo f32, out FLOAT32.
// ---------------------------------------------------------------------------
__global__ __launch_bounds__(256) void out_proj_kernel(
    const bf16* __restrict__ Xa, const float* __restrict__ Wo,
    const float* __restrict__ bo, float* __restrict__ out)
{
    const int lane = threadIdx.x & 63;
    const int w    = threadIdx.x >> 6;
    const int lr = lane & 15, lq = lane >> 4;
    const int m0 = blockIdx.y*128 + (w>>1)*64;
    const int n0 = blockIdx.x*128 + (w&1)*64;

    f32x4 acc[4][4] = {};
    const bf16*  Ab = Xa + (size_t)(m0+lr)*DM + lq*8;
    const float* Bb = Wo + (size_t)(n0+lr)*DM + lq*8;
    for (int k0 = 0; k0 < DM; k0 += 32) {
        bf16x8 af[4], bfr[4];
        #pragma unroll
        for (int mi=0;mi<4;mi++) af[mi]  = ld8 (Ab + (size_t)mi*16*DM + k0);
        #pragma unroll
        for (int ni=0;ni<4;ni++) bfr[ni] = ld8f(Bb + (size_t)ni*16*DM + k0);
        #pragma unroll
        for (int mi=0;mi<4;mi++)
            #pragma unroll
            for (int ni=0;ni<4;ni++)
                acc[mi][ni] = MFMA16(af[mi], bfr[ni], acc[mi][ni]);
    }
    #pragma unroll
    for (int mi=0;mi<4;mi++)
    #pragma unroll
    for (int ni=0;ni<4;ni++)
    #pragma unroll
    for (int r=0;r<4;r++) {
        int row = m0 + mi*16 + lq*4 + r;
        int col = n0 + ni*16 + lr;
        out[(size_t)row*DM + col] = acc[mi][ni][r] + bo[col];
    }
}

// ---------------------------------------------------------------------------
extern "C" void kernel_launch(void* const* d_in, const int* in_sizes, int n_in,
                              void* d_out, int out_size, void* d_ws, size_t ws_size,
                              hipStream_t stream)
{
    const float* Q  = (const float*)d_in[0];
    const float* K  = (const float*)d_in[1];
    const float* V  = (const float*)d_in[2];
    const float* Wq = (const float*)d_in[3];
    const float* Wk = (const float*)d_in[4];
    const float* Wv = (const float*)d_in[5];
    const float* Wo = (const float*)d_in[6];
    const float* bo = (const float*)d_in[7];
    float* out = (float*)d_out;

    bf16* ws = (bf16*)d_ws;
    const size_t NTOK = (size_t)BATCH*SEQ*DM;   // 4,194,304 elements
    bf16* q_s  = ws;
    bf16* k_s  = ws + NTOK;
    bf16* vt_s = ws + 2*NTOK;
    bf16* ao   = ws + 3*NTOK;                   // 32 MB of ws total

    qkv_proj_kernel<<<dim3(8,32,3), 256, 0, stream>>>(Q,K,V,Wq,Wk,Wv,q_s,k_s,vt_s);
    attn_kernel<<<dim3(32,32), 256, 0, stream>>>(q_s,k_s,vt_s, out + NTOK, ao);
    out_proj_kernel<<<dim3(8,32), 256, 0, stream>>>(ao,Wo,bo,out);
}